// Round 9
// baseline (1369.978 us; speedup 1.0000x reference)
//
#include <hip/hip_runtime.h>

typedef _Float16 half8 __attribute__((ext_vector_type(8)));
typedef float floatx4 __attribute__((ext_vector_type(4)));

#define T_STEPS 20
#define NSEQ 131072
#define HID 192
#define ROWS 32
#define HPAD 200            // fp16 elems per LDS h-row; cols 192..194 = [x.x, x.y, 1]
#define HROWS 17            // 16 rows + zero guard row (kc6 quad over-read)
#define WOFF 147456         // frags: wout section      (3072 halfs)
#define XOFF 150528         // frags: w_ih/bias section (6144 halfs, compact q==0 layout)
#define FR_TOTAL (XOFF + 6144)

#define MFMA16(a, b, c) __builtin_amdgcn_mfma_f32_16x16x32_f16((a), (b), (c), 0, 0, 0)

// Rewrite w_hh / w_out / (w_ih,b) into MFMA B-fragment order (fp16).
// B-frag 16x16x32: lane L = q*16 + n holds k = q*8..q*8+7 of column n.
// W_hh section: [12 ht][6 kc][4 g][64 lanes][8 e]
// WX section:   [12 ht][4 g][16 n][8 e] compact — only the q==0 rows (k<8):
//               e0 = w_ih[col][0], e1 = w_ih[col][1], e2 = b_ih[col]+b_hh[col], e3..7 = 0
__global__ void build_frags(const float* __restrict__ whh,
                            const float* __restrict__ wout,
                            const float* __restrict__ wih,
                            const float* __restrict__ bih,
                            const float* __restrict__ bhh,
                            _Float16* __restrict__ dst) {
    int i = blockIdx.x * 256 + threadIdx.x;
    if (i < WOFF) {
        int e = i & 7, L = (i >> 3) & 63, g = (i >> 9) & 3, u = i >> 11;
        int kc = u % 6, ht = u / 6;
        int n = L & 15, q = L >> 4;
        dst[i] = (_Float16)whh[(size_t)(g * HID + ht * 16 + n) * HID + kc * 32 + q * 8 + e];
    } else if (i < XOFF) {
        int k = i - WOFF;
        int e = k & 7, L = (k >> 3) & 63, kc = k >> 9;
        int n = L & 15, q = L >> 4;
        dst[i] = (_Float16)((n < 2) ? wout[n * HID + kc * 32 + q * 8 + e] : 0.f);
    } else if (i < FR_TOTAL) {
        int k = i - XOFF;
        int e = k & 7, n = (k >> 3) & 15, g = (k >> 7) & 3, ht = k >> 9;
        int col = g * HID + ht * 16 + n;
        float v = 0.f;
        if (e == 0)      v = wih[col * 2];
        else if (e == 1) v = wih[col * 2 + 1];
        else if (e == 2) v = bih[col] + bhh[col];
        dst[i] = (_Float16)v;
    }
}

// 768 threads = 12 waves, 1 block/CU. Round-8 structure (skewed two-half
// schedule, SGB interleave, kc0-3 + bx register-resident, balanced wout)
// with ONE change: kc4-5 B-frags are read from L2 via global loads placed
// at EXACTLY round-8's ds_read positions (same ~1-unit lead, same ~24-reg
// liveness window — round 7's spill came from its 2-3-unit VMEM lead, not
// from VMEM itself; round 0 ran 16 VMEM frags/step at 76 VGPRs cleanly).
// Moves ~1150 cyc/CU-segment off the top pipe (LDS 55% busy) onto the
// idle VMEM pipe; b_lds (96 KB) deleted.
__global__ __launch_bounds__(768) __attribute__((amdgpu_waves_per_eu(3, 3)))
void lstm_fused_kernel(
    const float* __restrict__ obs,       // [20][N][2]
    const float* __restrict__ h0,        // [N][192]
    const float* __restrict__ b_out,     // [2]
    const _Float16* __restrict__ frags,  // whh + wout + wx fragments (fp16)
    float* __restrict__ out)             // [20][N][2]
{
    __shared__ _Float16 h0b[2][HROWS][HPAD];  // rows 0..15, double-buffered (13600 B)
    __shared__ _Float16 h1b[HROWS][HPAD];     // rows 16..31, single-buffered (6800 B)
    __shared__ _Float16 wo_lds[3072];         // wout frags (6144 B)
    __shared__ float2 x_all[T_STEPS][ROWS];   // all steps' x (5120 B)

    const int tid  = threadIdx.x;
    const int wave = tid >> 6;
    const int lane = tid & 63;
    const int quad = lane >> 4;
    const int l16  = lane & 15;
    const int ht   = wave;
    const int base = blockIdx.x * ROWS;
    const int j    = ht * 16 + l16;

    const half8 HZ = {0, 0, 0, 0, 0, 0, 0, 0};

    // ---- resident weights: whh kc0..3 B-frags (64 VGPRs) + kc6 x/bias (16) ----
    half8 bw[16], bx[4];
#pragma unroll
    for (int kc = 0; kc < 4; ++kc)
#pragma unroll
        for (int g = 0; g < 4; ++g)
            bw[kc * 4 + g] = *(const half8*)&frags[(((ht * 6 + kc) * 4 + g) << 9) + lane * 8];
#pragma unroll
    for (int g = 0; g < 4; ++g)
        bx[g] = (quad == 0)
              ? *(const half8*)&frags[XOFF + ht * 512 + g * 128 + l16 * 8]
              : HZ;   // quads 1..3 contribute zero (their A over-read is nulled)

    // per-wave L2 stream base for kc4-5 B-frags: b(k2,g) at +(k2*4+g)*512
    const _Float16* wgp = frags + (((size_t)(ht * 6 + 4) * 4) << 9) + lane * 8;

    // ---- staging phase A: zero h-buffers, stage wout / x ----
    for (int i = tid; i < 2 * HROWS * HPAD / 8; i += 768) ((half8*)h0b)[i] = HZ;
    for (int i = tid; i < HROWS * HPAD / 8; i += 768)     ((half8*)h1b)[i] = HZ;
    if (tid < 384) ((half8*)wo_lds)[tid] = *(const half8*)&frags[WOFF + tid * 8];
    if (tid < T_STEPS * ROWS) {
        int t = tid >> 5, r = tid & 31;
        int src = (t == 0) ? 0 : (t - 1);
        x_all[t][r] = *(const float2*)&obs[((size_t)src * NSEQ + base + r) * 2];
    }
    __syncthreads();

    // ---- staging phase B: h0 -> fp16 rows; x_0; the '1' column ----
    for (int i = tid; i < ROWS * HID / 4; i += 768) {
        float4 v = *(const float4*)&h0[(size_t)base * HID + i * 4];
        int row = (i * 4) / HID, k = i * 4 - row * HID;
        _Float16* d = (row < 16) ? &h0b[0][row][k] : &h1b[row - 16][k];
        d[0] = (_Float16)v.x; d[1] = (_Float16)v.y;
        d[2] = (_Float16)v.z; d[3] = (_Float16)v.w;
    }
    if (tid < 64) {
        int row = tid >> 1;
        _Float16 v = (_Float16)((const float*)x_all[0])[tid];
        if (row < 16) h0b[0][row][192 + (tid & 1)] = v;
        else          h1b[row - 16][192 + (tid & 1)] = v;
    }
    if (tid < 16)      { h0b[0][tid][194] = (_Float16)1.f; h0b[1][tid][194] = (_Float16)1.f; }
    else if (tid < 32)   h1b[tid - 16][194] = (_Float16)1.f;
    __syncthreads();

    const float bo_n = (l16 < 2) ? b_out[l16] : 0.f;

    float c[8];
#pragma unroll
    for (int i = 0; i < 8; ++i) c[i] = 0.f;

    // gate MFMAs for one 16-row half: kc6 (regs, C = inline 0) + kc0..3 (regs)
    // + kc4..5 streamed from L2 at round-8's read positions (no extra lead).
    auto build = [&](const _Float16* hb, floatx4* aN) {
        const _Float16* ar = hb + l16 * HPAD;
        const _Float16* wgl = wgp;
        asm volatile("" : "+v"(wgl));     // opaque ptr: defeat LICM of the stream

        half8 ax = *(const half8*)(ar + 192 + quad * 8);   // quads 1-3 over-read: B=0
#pragma unroll
        for (int g = 0; g < 4; ++g)
            aN[g] = MFMA16(ax, bx[g], ((floatx4){0.f, 0.f, 0.f, 0.f}));
#pragma unroll
        for (int kc = 0; kc < 4; ++kc) {
            half8 a = *(const half8*)(ar + kc * 32 + quad * 8);
#pragma unroll
            for (int g = 0; g < 4; ++g)
                aN[g] = MFMA16(a, bw[kc * 4 + g], aN[g]);
        }
#pragma unroll
        for (int k2 = 0; k2 < 2; ++k2) {
            half8 a = *(const half8*)(ar + (4 + k2) * 32 + quad * 8);
#pragma unroll
            for (int g = 0; g < 4; ++g) {
                half8 b = *(const half8*)(wgl + (((k2 * 4 + g)) << 9));
                aN[g] = MFMA16(a, b, aN[g]);
            }
        }
    };

    // activation (rational form: 5 exp2 + 2 rcp per cell)
    auto act = [&](floatx4* aO, _Float16* hw, int cb) {
#pragma unroll
        for (int r = 0; r < 4; ++r) {
            const int row = quad * 4 + r;
            const float Ai = __builtin_amdgcn_exp2f(-1.4426950408889634f * aO[0][r]);
            const float Af = __builtin_amdgcn_exp2f(-1.4426950408889634f * aO[1][r]);
            const float Bg = __builtin_amdgcn_exp2f( 2.8853900817779268f * aO[2][r]);
            const float Co = __builtin_amdgcn_exp2f(-1.4426950408889634f * aO[3][r]);
            const float Qf = 1.f + Af;
            const float Pg = (1.f + Ai) * (Bg + 1.f);
            const float Nn = c[cb + r] * Pg + Qf * (Bg - 1.f);
            const float cn = Nn * __builtin_amdgcn_rcpf(Qf * Pg);
            c[cb + r] = cn;
            const float Dc = __builtin_amdgcn_exp2f(2.8853900817779268f * cn);
            const float hv = (Dc - 1.f) * __builtin_amdgcn_rcpf((1.f + Co) * (Dc + 1.f));
            hw[row * HPAD + j] = (_Float16)hv;
        }
    };

    // T19 pin: identical shape to round 8, with the 8 weight reads as
    // VMEM_READ (0x20) groups in the same positions the DS groups held.
    auto sched_pattern = [&]() {
        __builtin_amdgcn_sched_group_barrier(0x100, 2, 0);   // ax, a0
        __builtin_amdgcn_sched_group_barrier(0x002, 8, 0);   // early act VALU
#pragma unroll
        for (int u = 0; u < 3; ++u) {                        // kc6, kc0, kc1 MFMAs
            __builtin_amdgcn_sched_group_barrier(0x100, 1, 0);   // a1 / a2 / a3
            __builtin_amdgcn_sched_group_barrier(0x008, 4, 0);
            __builtin_amdgcn_sched_group_barrier(0x002, 10, 0);
        }
        __builtin_amdgcn_sched_group_barrier(0x100, 1, 0);   // a4
        __builtin_amdgcn_sched_group_barrier(0x020, 2, 0);   // b40, b41
        __builtin_amdgcn_sched_group_barrier(0x008, 4, 0);   // kc2 MFMAs
        __builtin_amdgcn_sched_group_barrier(0x002, 10, 0);
        __builtin_amdgcn_sched_group_barrier(0x020, 2, 0);   // b42, b43
        __builtin_amdgcn_sched_group_barrier(0x100, 1, 0);   // a5
        __builtin_amdgcn_sched_group_barrier(0x008, 4, 0);   // kc3 MFMAs
        __builtin_amdgcn_sched_group_barrier(0x002, 10, 0);
        __builtin_amdgcn_sched_group_barrier(0x020, 4, 0);   // b50..b53
        __builtin_amdgcn_sched_group_barrier(0x008, 8, 0);   // kc4+kc5 MFMAs
        __builtin_amdgcn_sched_group_barrier(0x002, 10, 0);
        __builtin_amdgcn_sched_group_barrier(0x200, 4, 0);   // DS_WRITE (h)
    };

    // wout for one 16-row half (wave 0 -> rows 0..15, wave 1 -> rows 16..31)
    auto wout1 = [&](int ot, const _Float16* hbase) {
        const _Float16* ar = hbase + l16 * HPAD;
        floatx4 ao = {bo_n, bo_n, bo_n, bo_n};
#pragma unroll
        for (int kc = 0; kc < 6; ++kc) {
            half8 a = *(const half8*)(ar + kc * 32 + quad * 8);
            half8 b = *(const half8*)&wo_lds[kc * 512 + lane * 8];
            ao = MFMA16(a, b, ao);
        }
        if (l16 < 2) {
#pragma unroll
            for (int r = 0; r < 4; ++r)
                out[((size_t)ot * NSEQ + base + ht * 16 + quad * 4 + r) * 2 + l16] = ao[r];
        }
    };

    // ---- prologue: accA = gates for half0 at t=0 ----
    floatx4 accA[4], accB[4];
    build(&h0b[0][0][0], accA);

    for (int t = 0; t < T_STEPS - 1; ++t) {
        _Float16* h0n = &h0b[(t + 1) & 1][0][0];

        // ===== segment X: H1 gate MFMAs || act(accA) -> next H0 || ht1 wout =====
        build(&h1b[0][0], accB);
        act(accA, h0n, 0);
        sched_pattern();
        if (ht == 1 && t > 0)
            wout1(t - 1, &h1b[0][0]);          // h_t rows16-31 (h1b stable in X)
        if (ht == 10 && lane < 32)
            h0n[(lane >> 1) * HPAD + 192 + (lane & 1)] =
                (_Float16)((const float*)x_all[t + 1])[lane];
        __syncthreads();

        // ===== segment Y: next-H0 gate MFMAs || act(accB) -> H1 || ht0 wout =====
        build(h0n, accA);
        act(accB, &h1b[0][0], 4);
        sched_pattern();
        if (ht == 0 && t > 0)
            wout1(t - 1, &h0b[t & 1][0][0]);   // h_t rows0-15 (dbuf-stable in Y)
        if (ht == 11 && lane < 32)
            h1b[lane >> 1][192 + (lane & 1)] =
                (_Float16)((const float*)x_all[t + 1])[32 + lane];
        __syncthreads();
    }

    // ---- t = 19 peeled ----
    build(&h1b[0][0], accB);
    act(accA, &h0b[0][0][0], 0);               // h_20 rows0-15 -> h0b[0]
    sched_pattern();
    if (ht < 2)
        wout1(18, (ht == 0) ? &h0b[1][0][0] : &h1b[0][0]);   // h_19
    __syncthreads();
    act(accB, &h1b[0][0], 4);                  // h_20 rows16-31
    __syncthreads();
    if (ht < 2)
        wout1(19, (ht == 0) ? &h0b[0][0][0] : &h1b[0][0]);   // h_20
}

extern "C" void kernel_launch(void* const* d_in, const int* in_sizes, int n_in,
                              void* d_out, int out_size, void* d_ws, size_t ws_size,
                              hipStream_t stream) {
    const float* obs  = (const float*)d_in[0];
    const float* h0   = (const float*)d_in[1];
    const float* wih  = (const float*)d_in[2];
    const float* whh  = (const float*)d_in[3];
    const float* bih  = (const float*)d_in[4];
    const float* bhh  = (const float*)d_in[5];
    const float* wout = (const float*)d_in[6];
    const float* bout = (const float*)d_in[7];
    float* out = (float*)d_out;
    _Float16* frags = (_Float16*)d_ws;   // 313344 B used

    build_frags<<<(FR_TOTAL + 255) / 256, 256, 0, stream>>>(whh, wout, wih, bih, bhh, frags);
    lstm_fused_kernel<<<NSEQ / ROWS, 768, 0, stream>>>(obs, h0, bout, frags, out);
}

// Round 10
// 1156.822 us; speedup vs baseline: 1.1843x; 1.1843x over previous
//
#include <hip/hip_runtime.h>

typedef _Float16 half8 __attribute__((ext_vector_type(8)));
typedef float floatx4 __attribute__((ext_vector_type(4)));

#define T_STEPS 20
#define NSEQ 131072
#define HID 192
#define ROWS 32
#define HPAD 200            // fp16 elems per LDS h-row; cols 192..194 = [x.x, x.y, 1]
#define HROWS 17            // 16 rows + zero guard row (kc6 quad over-read)
#define WOFF 147456         // frags: wout section      (3072 halfs)
#define XOFF 150528         // frags: w_ih/bias section (6144 halfs, compact q==0 layout)
#define FR_TOTAL (XOFF + 6144)

#define MFMA16(a, b, c) __builtin_amdgcn_mfma_f32_16x16x32_f16((a), (b), (c), 0, 0, 0)

// Rewrite w_hh / w_out / (w_ih,b) into MFMA B-fragment order (fp16).
// B-frag 16x16x32: lane L = q*16 + n holds k = q*8..q*8+7 of column n.
// W_hh section: [12 ht][6 kc][4 g][64 lanes][8 e]
// WX section:   [12 ht][4 g][16 n][8 e] compact — only the q==0 rows (k<8):
//               e0 = w_ih[col][0], e1 = w_ih[col][1], e2 = b_ih[col]+b_hh[col], e3..7 = 0
__global__ void build_frags(const float* __restrict__ whh,
                            const float* __restrict__ wout,
                            const float* __restrict__ wih,
                            const float* __restrict__ bih,
                            const float* __restrict__ bhh,
                            _Float16* __restrict__ dst) {
    int i = blockIdx.x * 256 + threadIdx.x;
    if (i < WOFF) {
        int e = i & 7, L = (i >> 3) & 63, g = (i >> 9) & 3, u = i >> 11;
        int kc = u % 6, ht = u / 6;
        int n = L & 15, q = L >> 4;
        dst[i] = (_Float16)whh[(size_t)(g * HID + ht * 16 + n) * HID + kc * 32 + q * 8 + e];
    } else if (i < XOFF) {
        int k = i - WOFF;
        int e = k & 7, L = (k >> 3) & 63, kc = k >> 9;
        int n = L & 15, q = L >> 4;
        dst[i] = (_Float16)((n < 2) ? wout[n * HID + kc * 32 + q * 8 + e] : 0.f);
    } else if (i < FR_TOTAL) {
        int k = i - XOFF;
        int e = k & 7, n = (k >> 3) & 15, g = (k >> 7) & 3, ht = k >> 9;
        int col = g * HID + ht * 16 + n;
        float v = 0.f;
        if (e == 0)      v = wih[col * 2];
        else if (e == 1) v = wih[col * 2 + 1];
        else if (e == 2) v = bih[col] + bhh[col];
        dst[i] = (_Float16)v;
    }
}

// 768 threads = 12 waves, 1 block/CU (LDS ~135 KB). Round-8 incumbent
// (skewed two-half schedule, SGB interleave, kc0-3 + bx register-resident,
// kc4-5 in b_lds, balanced wout) with ONE change: wout results are staged
// in a 5 KB LDS buffer and bulk-stored in an epilogue. The main loop now
// has ZERO global-memory ops, so the compiler's `s_waitcnt vmcnt(0)`
// before each s_barrier is free — previously waves 0/1 waited ~hundreds
// of cycles for global_store acks at every barrier, and all 12 waves
// waited on them (store-drain on the barrier critical path, 40×/block).
// Locked-in lessons: ~168-reg unified envelope at 3 waves/EU (r4-r7);
// weights must be reg/LDS-resident, L2 too far at this dep depth (r9).
__global__ __launch_bounds__(768) __attribute__((amdgpu_waves_per_eu(3, 3)))
void lstm_fused_kernel(
    const float* __restrict__ obs,       // [20][N][2]
    const float* __restrict__ h0,        // [N][192]
    const float* __restrict__ b_out,     // [2]
    const _Float16* __restrict__ frags,  // whh + wout + wx fragments (fp16)
    float* __restrict__ out)             // [20][N][2]
{
    __shared__ _Float16 h0b[2][HROWS][HPAD];  // rows 0..15, double-buffered (13600 B)
    __shared__ _Float16 h1b[HROWS][HPAD];     // rows 16..31, single-buffered (6800 B)
    __shared__ _Float16 b_lds[49152];         // whh kc4,kc5: [12ht][2][4g][512] (98304 B)
    __shared__ _Float16 wo_lds[3072];         // wout frags (6144 B)
    __shared__ float2 x_all[T_STEPS][ROWS];   // all steps' x (5120 B)
    __shared__ alignas(16) float out_lds[T_STEPS][ROWS][2];  // staged out (5120 B)

    const int tid  = threadIdx.x;
    const int wave = tid >> 6;
    const int lane = tid & 63;
    const int quad = lane >> 4;
    const int l16  = lane & 15;
    const int ht   = wave;
    const int base = blockIdx.x * ROWS;
    const int j    = ht * 16 + l16;

    const half8 HZ = {0, 0, 0, 0, 0, 0, 0, 0};

    // ---- resident weights: whh kc0..3 B-frags (64 VGPRs) + kc6 x/bias (16) ----
    half8 bw[16], bx[4];
#pragma unroll
    for (int kc = 0; kc < 4; ++kc)
#pragma unroll
        for (int g = 0; g < 4; ++g)
            bw[kc * 4 + g] = *(const half8*)&frags[(((ht * 6 + kc) * 4 + g) << 9) + lane * 8];
#pragma unroll
    for (int g = 0; g < 4; ++g)
        bx[g] = (quad == 0)
              ? *(const half8*)&frags[XOFF + ht * 512 + g * 128 + l16 * 8]
              : HZ;   // quads 1..3 contribute zero (their A over-read is nulled)

    // ---- staging phase A: zero h-buffers, stage kc4-5 / wout / x ----
    for (int i = tid; i < 2 * HROWS * HPAD / 8; i += 768) ((half8*)h0b)[i] = HZ;
    for (int i = tid; i < HROWS * HPAD / 8; i += 768)     ((half8*)h1b)[i] = HZ;
    for (int i = tid; i < 6144; i += 768) {   // b_lds <- whh kc4,kc5
        int g = (i >> 6) & 3, u = i >> 8, k2 = u & 1, h = u >> 1;
        ((half8*)b_lds)[i] = *(const half8*)&frags[(((h * 6 + 4 + k2) * 4 + g) << 9) + (i & 63) * 8];
    }
    if (tid < 384) ((half8*)wo_lds)[tid] = *(const half8*)&frags[WOFF + tid * 8];
    if (tid < T_STEPS * ROWS) {
        int t = tid >> 5, r = tid & 31;
        int src = (t == 0) ? 0 : (t - 1);
        x_all[t][r] = *(const float2*)&obs[((size_t)src * NSEQ + base + r) * 2];
    }
    __syncthreads();

    // ---- staging phase B: h0 -> fp16 rows; x_0; the '1' column ----
    for (int i = tid; i < ROWS * HID / 4; i += 768) {
        float4 v = *(const float4*)&h0[(size_t)base * HID + i * 4];
        int row = (i * 4) / HID, k = i * 4 - row * HID;
        _Float16* d = (row < 16) ? &h0b[0][row][k] : &h1b[row - 16][k];
        d[0] = (_Float16)v.x; d[1] = (_Float16)v.y;
        d[2] = (_Float16)v.z; d[3] = (_Float16)v.w;
    }
    if (tid < 64) {
        int row = tid >> 1;
        _Float16 v = (_Float16)((const float*)x_all[0])[tid];
        if (row < 16) h0b[0][row][192 + (tid & 1)] = v;
        else          h1b[row - 16][192 + (tid & 1)] = v;
    }
    if (tid < 16)      { h0b[0][tid][194] = (_Float16)1.f; h0b[1][tid][194] = (_Float16)1.f; }
    else if (tid < 32)   h1b[tid - 16][194] = (_Float16)1.f;
    __syncthreads();

    const float bo_n = (l16 < 2) ? b_out[l16] : 0.f;

    float c[8];
#pragma unroll
    for (int i = 0; i < 8; ++i) c[i] = 0.f;

    // gate MFMAs for one 16-row half: kc6 (regs, C = inline 0) + kc0..3 (regs)
    // + kc4..5 (LDS). The kc6 MFMA doubles as the accumulator init.
    auto build = [&](const _Float16* hb, floatx4* aN) {
        const _Float16* ar = hb + l16 * HPAD;
        const _Float16* blp = b_lds;
        asm volatile("" : "+v"(blp));     // defeat LICM of the b-frag ds_reads

        half8 ax = *(const half8*)(ar + 192 + quad * 8);   // quads 1-3 over-read: B=0
#pragma unroll
        for (int g = 0; g < 4; ++g)
            aN[g] = MFMA16(ax, bx[g], ((floatx4){0.f, 0.f, 0.f, 0.f}));
#pragma unroll
        for (int kc = 0; kc < 4; ++kc) {
            half8 a = *(const half8*)(ar + kc * 32 + quad * 8);
#pragma unroll
            for (int g = 0; g < 4; ++g)
                aN[g] = MFMA16(a, bw[kc * 4 + g], aN[g]);
        }
#pragma unroll
        for (int k2 = 0; k2 < 2; ++k2) {
            half8 a = *(const half8*)(ar + (4 + k2) * 32 + quad * 8);
#pragma unroll
            for (int g = 0; g < 4; ++g) {
                half8 b = *(const half8*)&blp[(((ht * 2 + k2) * 4 + g) << 9) + lane * 8];
                aN[g] = MFMA16(a, b, aN[g]);
            }
        }
    };

    // activation (rational form: 5 exp2 + 2 rcp per cell)
    auto act = [&](floatx4* aO, _Float16* hw, int cb) {
#pragma unroll
        for (int r = 0; r < 4; ++r) {
            const int row = quad * 4 + r;
            const float Ai = __builtin_amdgcn_exp2f(-1.4426950408889634f * aO[0][r]);
            const float Af = __builtin_amdgcn_exp2f(-1.4426950408889634f * aO[1][r]);
            const float Bg = __builtin_amdgcn_exp2f( 2.8853900817779268f * aO[2][r]);
            const float Co = __builtin_amdgcn_exp2f(-1.4426950408889634f * aO[3][r]);
            const float Qf = 1.f + Af;
            const float Pg = (1.f + Ai) * (Bg + 1.f);
            const float Nn = c[cb + r] * Pg + Qf * (Bg - 1.f);
            const float cn = Nn * __builtin_amdgcn_rcpf(Qf * Pg);
            c[cb + r] = cn;
            const float Dc = __builtin_amdgcn_exp2f(2.8853900817779268f * cn);
            const float hv = (Dc - 1.f) * __builtin_amdgcn_rcpf((1.f + Co) * (Dc + 1.f));
            hw[row * HPAD + j] = (_Float16)hv;
        }
    };

    // T19 pin (round-3/8 proven): per unit {DS_READ(s), 4 MFMA, act VALU}.
    auto sched_pattern = [&]() {
        __builtin_amdgcn_sched_group_barrier(0x100, 2, 0);   // ax + first a
        __builtin_amdgcn_sched_group_barrier(0x002, 8, 0);   // early act VALU
#pragma unroll
        for (int u = 0; u < 4; ++u) {                        // kc6 + kc0..2
            __builtin_amdgcn_sched_group_barrier(0x100, 1, 0);
            __builtin_amdgcn_sched_group_barrier(0x008, 4, 0);
            __builtin_amdgcn_sched_group_barrier(0x002, 10, 0);
        }
        __builtin_amdgcn_sched_group_barrier(0x100, 3, 0);   // kc3 a + kc4 b pair
        __builtin_amdgcn_sched_group_barrier(0x008, 4, 0);
        __builtin_amdgcn_sched_group_barrier(0x002, 10, 0);
        __builtin_amdgcn_sched_group_barrier(0x100, 3, 0);   // kc5 a + b pair
        __builtin_amdgcn_sched_group_barrier(0x008, 4, 0);
        __builtin_amdgcn_sched_group_barrier(0x002, 10, 0);
        __builtin_amdgcn_sched_group_barrier(0x100, 4, 0);   // remaining b frags
        __builtin_amdgcn_sched_group_barrier(0x008, 8, 0);   // kc4+kc5 MFMAs
        __builtin_amdgcn_sched_group_barrier(0x002, 10, 0);
        __builtin_amdgcn_sched_group_barrier(0x200, 4, 0);   // DS_WRITE (h)
    };

    // wout for one 16-row half (ht 0 -> rows 0..15, ht 1 -> rows 16..31).
    // Results go to out_lds (NO global store in the loop -> vmcnt(0) at the
    // barriers is free; bulk store happens in the epilogue).
    auto wout1 = [&](int ot, const _Float16* hbase) {
        const _Float16* ar = hbase + l16 * HPAD;
        floatx4 ao = {bo_n, bo_n, bo_n, bo_n};
#pragma unroll
        for (int kc = 0; kc < 6; ++kc) {
            half8 a = *(const half8*)(ar + kc * 32 + quad * 8);
            half8 b = *(const half8*)&wo_lds[kc * 512 + lane * 8];
            ao = MFMA16(a, b, ao);
        }
        if (l16 < 2) {
#pragma unroll
            for (int r = 0; r < 4; ++r)
                out_lds[ot][ht * 16 + quad * 4 + r][l16] = ao[r];
        }
    };

    // ---- prologue: accA = gates for half0 at t=0 ----
    floatx4 accA[4], accB[4];
    build(&h0b[0][0][0], accA);

    for (int t = 0; t < T_STEPS - 1; ++t) {
        _Float16* h0n = &h0b[(t + 1) & 1][0][0];

        // ===== segment X: H1 gate MFMAs || act(accA) -> next H0 || ht1 wout =====
        build(&h1b[0][0], accB);
        act(accA, h0n, 0);
        sched_pattern();
        if (ht == 1 && t > 0)
            wout1(t - 1, &h1b[0][0]);          // h_t rows16-31 (h1b stable in X)
        if (ht == 10 && lane < 32)
            h0n[(lane >> 1) * HPAD + 192 + (lane & 1)] =
                (_Float16)((const float*)x_all[t + 1])[lane];
        __syncthreads();

        // ===== segment Y: next-H0 gate MFMAs || act(accB) -> H1 || ht0 wout =====
        build(h0n, accA);
        act(accB, &h1b[0][0], 4);
        sched_pattern();
        if (ht == 0 && t > 0)
            wout1(t - 1, &h0b[t & 1][0][0]);   // h_t rows0-15 (dbuf-stable in Y)
        if (ht == 11 && lane < 32)
            h1b[lane >> 1][192 + (lane & 1)] =
                (_Float16)((const float*)x_all[t + 1])[32 + lane];
        __syncthreads();
    }

    // ---- t = 19 peeled ----
    build(&h1b[0][0], accB);
    act(accA, &h0b[0][0][0], 0);               // h_20 rows0-15 -> h0b[0]
    sched_pattern();
    if (ht < 2)
        wout1(18, (ht == 0) ? &h0b[1][0][0] : &h1b[0][0]);   // h_19
    __syncthreads();
    act(accB, &h1b[0][0], 4);                  // h_20 rows16-31
    __syncthreads();
    if (ht < 2)
        wout1(19, (ht == 0) ? &h0b[0][0][0] : &h1b[0][0]);   // h_20

    // ---- epilogue: bulk-store the staged outputs (the only global stores) ----
    __syncthreads();
    for (int i = tid; i < T_STEPS * ROWS; i += 768) {
        int t = i >> 5, row = i & 31;
        *(float2*)&out[((size_t)t * NSEQ + base + row) * 2] =
            *(const float2*)&out_lds[t][row][0];
    }
}

extern "C" void kernel_launch(void* const* d_in, const int* in_sizes, int n_in,
                              void* d_out, int out_size, void* d_ws, size_t ws_size,
                              hipStream_t stream) {
    const float* obs  = (const float*)d_in[0];
    const float* h0   = (const float*)d_in[1];
    const float* wih  = (const float*)d_in[2];
    const float* whh  = (const float*)d_in[3];
    const float* bih  = (const float*)d_in[4];
    const float* bhh  = (const float*)d_in[5];
    const float* wout = (const float*)d_in[6];
    const float* bout = (const float*)d_in[7];
    float* out = (float*)d_out;
    _Float16* frags = (_Float16*)d_ws;   // 313344 B used

    build_frags<<<(FR_TOTAL + 255) / 256, 256, 0, stream>>>(whh, wout, wih, bih, bhh, frags);
    lstm_fused_kernel<<<NSEQ / ROWS, 768, 0, stream>>>(obs, h0, bout, frags, out);
}